// Round 3
// baseline (212.778 us; speedup 1.0000x reference)
//
#include <hip/hip_runtime.h>

#define T_STEPS 256
#define B_SZ 128
#define I_SZ 1024
#define O_SZ 512

typedef short bf16x8 __attribute__((ext_vector_type(8)));
typedef float f32x16 __attribute__((ext_vector_type(16)));

#define PLANE (O_SZ * I_SZ)                 // ushorts per split plane
#define WS_NEEDED ((size_t)3 * PLANE * 2)   // 3 MB

// ---------------------------------------------------------------------------
// helpers
// ---------------------------------------------------------------------------
__device__ __forceinline__ ushort f2bf_rne(float f) {
    uint u = __float_as_uint(f);
    u += ((u >> 16) & 1u) + 0x7fffu;        // round-to-nearest-even
    return (ushort)(u >> 16);
}
__device__ __forceinline__ uint pk2(float lo, float hi) {
    // exact for x in {0,1}: truncation == RNE
    return (__float_as_uint(lo) >> 16) | (__float_as_uint(hi) & 0xffff0000u);
}
__device__ __forceinline__ void gload_lds16(const void* g, void* l) {
    typedef const void __attribute__((address_space(1))) gvt;
    typedef void __attribute__((address_space(3))) svt;
    __builtin_amdgcn_global_load_lds((gvt*)g, (svt*)l, 16, 0, 0);
}

// ---------------------------------------------------------------------------
// W split: W[n][k] fp32 -> 3 bf16 planes in MFMA-fragment order:
//   plane[p] layout [kt(32)][nsg(16)][k16(2)][lane(64)][8]
//   element (n,k): kt=k>>5, k16=(k>>4)&1, kh=(k>>3)&1, l=(n&31)|(kh<<5),
//   j=k&7, nsg=n>>5
// ---------------------------------------------------------------------------
__global__ __launch_bounds__(256) void wsplit_kernel(
    const float* __restrict__ W, ushort* __restrict__ wsp)
{
    const int t = blockIdx.x * 256 + threadIdx.x;   // 65536 threads
    const int n = t >> 7, kq = t & 127, k0 = kq * 8;
    const float* wp = W + (size_t)n * I_SZ + k0;

    uint q1[4], q2[4], q3[4];
#pragma unroll
    for (int jj = 0; jj < 4; ++jj) {
        ushort s1[2], s2[2], s3[2];
#pragma unroll
        for (int e = 0; e < 2; ++e) {
            float w0 = wp[jj * 2 + e];
            ushort a1 = f2bf_rne(w0);
            float  f1 = __uint_as_float((uint)a1 << 16);
            float  r1 = w0 - f1;
            ushort a2 = f2bf_rne(r1);
            float  f2 = __uint_as_float((uint)a2 << 16);
            float  r2 = r1 - f2;
            ushort a3 = f2bf_rne(r2);
            s1[e] = a1; s2[e] = a2; s3[e] = a3;
        }
        q1[jj] = (uint)s1[0] | ((uint)s1[1] << 16);
        q2[jj] = (uint)s2[0] | ((uint)s2[1] << 16);
        q3[jj] = (uint)s3[0] | ((uint)s3[1] << 16);
    }
    const int kt = k0 >> 5, k16 = (k0 >> 4) & 1, kh = (k0 >> 3) & 1;
    const int l = (n & 31) | (kh << 5), nsg = n >> 5;
    const size_t off = ((((size_t)kt * 16 + nsg) * 2 + k16) * 64 + l) * 8;
    *(uint4*)(wsp + off)             = make_uint4(q1[0], q1[1], q1[2], q1[3]);
    *(uint4*)(wsp + PLANE + off)     = make_uint4(q2[0], q2[1], q2[2], q2[3]);
    *(uint4*)(wsp + 2 * PLANE + off) = make_uint4(q3[0], q3[1], q3[2], q3[3]);
}

// ---------------------------------------------------------------------------
// MFMA GEMM: S[M][O] = X[M][K](binary) @ (W1+W2+W3)^T + bias
//   256x256 tile, 8 waves (4m x 2n), per-wave 64x128, BK=32,
//   double-buffered LDS (128KB, 1 block/CU), single barrier per K-step.
//   A: reg-staged fp32->bf16 (exact for binary x); B: global_load_lds x6/wave.
// ---------------------------------------------------------------------------
__global__ __launch_bounds__(512, 2) void gemm_mfma2(
    const float* __restrict__ X, const ushort* __restrict__ wsp,
    const float* __restrict__ bias, float* __restrict__ S)
{
    __shared__ uint lds_u[32768];   // 2 bufs x (A 4096 uints | B 12288 uints)

    const int tid  = threadIdx.x;
    const int lane = tid & 63;
    const int w    = tid >> 6;          // 0..7
    const int wm   = w >> 1, wn = w & 1;

    // bijective XCD swizzle: 256 wgs, 8 XCDs, 32/XCD; nb-pairs of same mb adjacent
    const int bid     = blockIdx.x;
    const int logical = (bid & 7) * 32 + (bid >> 3);
    const int mb = logical >> 1, nb = logical & 1;
    const int row0 = mb * 256;

    // ---- A staging: thread owns fragment-lanes f0=2*tid, f0+1 (rows m0, m0+1)
    const int f0   = tid * 2;
    const int msub = f0 >> 7, k16s = (f0 >> 6) & 1, l0 = f0 & 63;
    const int m0   = msub * 32 + (l0 & 31);
    const int ks   = (l0 >> 5) * 8;
    const float* pa = X + (size_t)(row0 + m0) * I_SZ + k16s * 16 + ks;
    const int aoff = f0 * 4;            // uint offset within A region

    // ---- B staging: 48 x 1KB chunks per K-step; wave w issues chunks 6w..6w+5
    uint bsrc[6];
    const int c0 = w * 6;
#pragma unroll
    for (int i = 0; i < 6; ++i) {
        const int c = c0 + i, p = c >> 4, r = c & 15;
        const int nsgl = r >> 1, k16 = r & 1;
        bsrc[i] = (uint)p * PLANE + (uint)(((nb * 8 + nsgl) * 2 + k16) * 512) + lane * 8;
    }

    f32x16 acc[2][4];
#pragma unroll
    for (int i = 0; i < 2; ++i)
#pragma unroll
        for (int j = 0; j < 4; ++j)
#pragma unroll
            for (int r = 0; r < 16; ++r) acc[i][j][r] = 0.f;

    // ---- prologue: stage kt=0 into buf0
    {
        float4 a0 = *(const float4*)pa;
        float4 a1 = *(const float4*)(pa + 4);
        float4 a2 = *(const float4*)(pa + I_SZ);
        float4 a3 = *(const float4*)(pa + I_SZ + 4);
#pragma unroll
        for (int i = 0; i < 6; ++i)
            gload_lds16(wsp + bsrc[i], lds_u + 4096 + (c0 + i) * 256);
        uint* ad = lds_u + aoff;
        *(uint4*)ad       = make_uint4(pk2(a0.x, a0.y), pk2(a0.z, a0.w),
                                       pk2(a1.x, a1.y), pk2(a1.z, a1.w));
        *(uint4*)(ad + 4) = make_uint4(pk2(a2.x, a2.y), pk2(a2.z, a2.w),
                                       pk2(a3.x, a3.y), pk2(a3.z, a3.w));
        __syncthreads();
    }

    for (int kt = 0; kt < 32; ++kt) {
        const int cur = kt & 1;
        const uint* Au = lds_u + cur * 16384;
        const uint* Bu = Au + 4096;
        uint* nbase = lds_u + (cur ^ 1) * 16384;

        // stage kt+1: issue loads BEFORE the MFMA cluster
        float4 a0, a1, a2, a3;
        const bool pref = (kt < 31);
        if (pref) {
            const float* p0 = pa + (kt + 1) * 32;
            a0 = *(const float4*)p0;
            a1 = *(const float4*)(p0 + 4);
            a2 = *(const float4*)(p0 + I_SZ);
            a3 = *(const float4*)(p0 + I_SZ + 4);
            const uint kadd = (uint)(kt + 1) * 16384;
#pragma unroll
            for (int i = 0; i < 6; ++i)
                gload_lds16(wsp + bsrc[i] + kadd, nbase + 4096 + (c0 + i) * 256);
        }

        // compute current buffer: 48 MFMA
#pragma unroll
        for (int k16 = 0; k16 < 2; ++k16) {
            bf16x8 af0 = *(const bf16x8*)(Au + (wm * 4 + k16) * 256 + lane * 4);
            bf16x8 af1 = *(const bf16x8*)(Au + (wm * 4 + 2 + k16) * 256 + lane * 4);
#pragma unroll
            for (int p = 0; p < 3; ++p)
#pragma unroll
                for (int sn = 0; sn < 4; ++sn) {
                    const int c = (p * 8 + wn * 4 + sn) * 2 + k16;
                    bf16x8 bf = *(const bf16x8*)(Bu + c * 256 + lane * 4);
                    acc[0][sn] = __builtin_amdgcn_mfma_f32_32x32x16_bf16(af0, bf, acc[0][sn], 0, 0, 0);
                    acc[1][sn] = __builtin_amdgcn_mfma_f32_32x32x16_bf16(af1, bf, acc[1][sn], 0, 0, 0);
                }
        }

        // late A write into next buffer (loads have drained under the MFMAs)
        if (pref) {
            uint* ad = nbase + aoff;
            *(uint4*)ad       = make_uint4(pk2(a0.x, a0.y), pk2(a0.z, a0.w),
                                           pk2(a1.x, a1.y), pk2(a1.z, a1.w));
            *(uint4*)(ad + 4) = make_uint4(pk2(a2.x, a2.y), pk2(a2.z, a2.w),
                                           pk2(a3.x, a3.y), pk2(a3.z, a3.w));
        }
        __syncthreads();
    }

    // epilogue: D row=(reg&3)+8*(reg>>2)+4*(lane>>5), col=lane&31 (from B operand)
    const int colb = nb * 256 + wn * 128 + (lane & 31);
    const int rowb = row0 + wm * 64 + 4 * (lane >> 5);
    float bv[4];
#pragma unroll
    for (int sn = 0; sn < 4; ++sn) bv[sn] = bias[colb + sn * 32];
#pragma unroll
    for (int sm = 0; sm < 2; ++sm)
#pragma unroll
        for (int sn = 0; sn < 4; ++sn)
#pragma unroll
            for (int r = 0; r < 16; ++r) {
                const int rr = rowb + sm * 32 + (r & 3) + 8 * (r >> 2);
                S[(size_t)rr * O_SZ + colb + sn * 32] = acc[sm][sn][r] + bv[sn];
            }
}

// ---------------------------------------------------------------------------
// Fallback fp32 GEMM if ws too small for split planes.
// ---------------------------------------------------------------------------
#define BM 128
#define BN 128
#define BKF 32
#define LDT 132

__global__ __launch_bounds__(256, 2) void gemm_fp32(
    const float* __restrict__ X, const float* __restrict__ W,
    const float* __restrict__ bias, float* __restrict__ S)
{
    __shared__ float As[BKF][LDT];
    __shared__ float Ws[BKF][LDT];
    const int tid = threadIdx.x;
    const int nb = blockIdx.x & 3;
    const int mb = blockIdx.x >> 2;
    const int tx = (tid & 7) | ((tid & 128) >> 4);
    const int ty = (tid >> 3) & 15;
    const float* Ablk = X + (size_t)mb * BM * I_SZ;
    const float* Wblk = W + (size_t)nb * BN * I_SZ;
    const int skq = tid & 7;
    const int srow = tid >> 3;
    float acc[8][8];
#pragma unroll
    for (int i = 0; i < 8; ++i)
#pragma unroll
        for (int j = 0; j < 8; ++j) acc[i][j] = 0.f;
    for (int kt = 0; kt < I_SZ; kt += BKF) {
#pragma unroll
        for (int it = 0; it < 4; ++it) {
            const int row = srow + it * 32;
            float4 a = *(const float4*)(Ablk + (size_t)row * I_SZ + kt + skq * 4);
            As[skq * 4 + 0][row] = a.x; As[skq * 4 + 1][row] = a.y;
            As[skq * 4 + 2][row] = a.z; As[skq * 4 + 3][row] = a.w;
            float4 wv = *(const float4*)(Wblk + (size_t)row * I_SZ + kt + skq * 4);
            Ws[skq * 4 + 0][row] = wv.x; Ws[skq * 4 + 1][row] = wv.y;
            Ws[skq * 4 + 2][row] = wv.z; Ws[skq * 4 + 3][row] = wv.w;
        }
        __syncthreads();
#pragma unroll
        for (int kk = 0; kk < BKF; ++kk) {
            float4 a0 = *(const float4*)&As[kk][ty * 8];
            float4 a1 = *(const float4*)&As[kk][ty * 8 + 4];
            float4 w0 = *(const float4*)&Ws[kk][tx * 8];
            float4 w1 = *(const float4*)&Ws[kk][tx * 8 + 4];
            float av[8] = {a0.x, a0.y, a0.z, a0.w, a1.x, a1.y, a1.z, a1.w};
            float wv[8] = {w0.x, w0.y, w0.z, w0.w, w1.x, w1.y, w1.z, w1.w};
#pragma unroll
            for (int i = 0; i < 8; ++i)
#pragma unroll
                for (int j = 0; j < 8; ++j) acc[i][j] += av[i] * wv[j];
        }
        __syncthreads();
    }
    const int row0 = mb * BM + ty * 8;
    const int col0 = nb * BN + tx * 8;
    float bv[8];
#pragma unroll
    for (int j = 0; j < 8; ++j) bv[j] = bias[col0 + j];
#pragma unroll
    for (int i = 0; i < 8; ++i) {
        float4 o0 = {acc[i][0] + bv[0], acc[i][1] + bv[1], acc[i][2] + bv[2], acc[i][3] + bv[3]};
        float4 o1 = {acc[i][4] + bv[4], acc[i][5] + bv[5], acc[i][6] + bv[6], acc[i][7] + bv[7]};
        *(float4*)(S + (size_t)(row0 + i) * O_SZ + col0)     = o0;
        *(float4*)(S + (size_t)(row0 + i) * O_SZ + col0 + 4) = o1;
    }
}

// ---------------------------------------------------------------------------
// Scan: per-(b,o) sequential recurrence; 8-deep software prefetch (1 wave/SIMD
// occupancy -> latency must be hidden by in-flight loads, not TLP).
// ---------------------------------------------------------------------------
__global__ __launch_bounds__(256) void scan_kernel(
    float* __restrict__ out, const float* __restrict__ wl_arr)
{
#pragma clang fp contract(off)
    const int gid = blockIdx.x * 256 + threadIdx.x;   // b*O + o
    const float wl = wl_arr[gid & (O_SZ - 1)];
    const float decay_s = 0.8f;
    const float decay_m = 0.9f;

    float sb[8];
#pragma unroll
    for (int i = 0; i < 8; ++i) sb[i] = out[(size_t)i * (B_SZ * O_SZ) + gid];

    float ep = 0.f, u = 0.f, osp = 0.f, vref = 0.f, tpost = -1.f;
    for (int tb = 0; tb < T_STEPS; tb += 8) {
        const bool pf = (tb < T_STEPS - 8);
#pragma unroll
        for (int i = 0; i < 8; ++i) {
            const int t = tb + i;
            const size_t idx = (size_t)t * (B_SZ * O_SZ) + gid;
            float s = sb[i];
            if (pf) sb[i] = out[idx + (size_t)8 * (B_SZ * O_SZ)];  // prefetch t+8
            float iresp = s + osp * wl;
            ep = ep * decay_s + iresp;
            u  = u * decay_m + ep / 5.0f;
            if (vref > 0.f) u = 0.f;
            osp = (u > 1.0f) ? 1.f : 0.f;
            float v = 2.0f * osp + (vref - 1.0f);
            vref = v < 0.f ? 0.f : (v > 2.f ? 2.f : v);
            float cand = osp * ((float)t + 1.0f) - 1.0f;
            tpost = cand > tpost ? cand : tpost;
            out[idx] = osp;
        }
    }
    out[(size_t)T_STEPS * B_SZ * O_SZ + (size_t)B_SZ * I_SZ + gid] = tpost;
}

// ---------------------------------------------------------------------------
// times_pre: last spike time of x per (b,i); backward scan with early exit.
// ---------------------------------------------------------------------------
__global__ __launch_bounds__(256) void tpre_kernel(
    const float* __restrict__ x, float* __restrict__ out)
{
    const int gid = blockIdx.x * 256 + threadIdx.x;
    float tp = -1.f;
    for (int t = T_STEPS - 1; t >= 0; --t) {
        if (x[(size_t)t * (B_SZ * I_SZ) + gid] > 0.5f) { tp = (float)t; break; }
    }
    out[(size_t)T_STEPS * B_SZ * O_SZ + gid] = tp;
}

// ---------------------------------------------------------------------------
extern "C" void kernel_launch(void* const* d_in, const int* in_sizes, int n_in,
                              void* d_out, int out_size, void* d_ws, size_t ws_size,
                              hipStream_t stream) {
    const float* x    = (const float*)d_in[0];
    const float* w    = (const float*)d_in[1];
    const float* bias = (const float*)d_in[2];
    const float* wl   = (const float*)d_in[3];
    float* out = (float*)d_out;

    if (ws_size >= WS_NEEDED) {
        ushort* wsp = (ushort*)d_ws;
        wsplit_kernel<<<dim3(256), dim3(256), 0, stream>>>(w, wsp);
        gemm_mfma2<<<dim3(256), dim3(512), 0, stream>>>(x, wsp, bias, out);
    } else {
        gemm_fp32<<<dim3(1024), dim3(256), 0, stream>>>(x, w, bias, out);
    }
    scan_kernel<<<dim3((B_SZ * O_SZ) / 256), dim3(256), 0, stream>>>(out, wl);
    tpre_kernel<<<dim3((B_SZ * I_SZ) / 256), dim3(256), 0, stream>>>(x, out);
}

// Round 4
// 146.865 us; speedup vs baseline: 1.4488x; 1.4488x over previous
//
#include <hip/hip_runtime.h>

#define T_STEPS 256
#define B_SZ 128
#define I_SZ 1024
#define O_SZ 512

typedef short bf16x8 __attribute__((ext_vector_type(8)));
typedef float f32x16 __attribute__((ext_vector_type(16)));

#define PLANE (O_SZ * I_SZ)                 // ushorts per split plane
#define WS_NEEDED ((size_t)3 * PLANE * 2)   // 3 MB

// ---------------------------------------------------------------------------
// helpers
// ---------------------------------------------------------------------------
__device__ __forceinline__ ushort f2bf_rne(float f) {
    uint u = __float_as_uint(f);
    u += ((u >> 16) & 1u) + 0x7fffu;        // round-to-nearest-even
    return (ushort)(u >> 16);
}
__device__ __forceinline__ uint pk2(float lo, float hi) {
    // exact for x in {0,1}: truncation == RNE
    return (__float_as_uint(lo) >> 16) | (__float_as_uint(hi) & 0xffff0000u);
}
__device__ __forceinline__ void gload_lds16(const void* g, void* l) {
    typedef const void __attribute__((address_space(1))) gvt;
    typedef void __attribute__((address_space(3))) svt;
    __builtin_amdgcn_global_load_lds((gvt*)g, (svt*)l, 16, 0, 0);
}

// ---------------------------------------------------------------------------
// W split: W[n][k] fp32 -> 3 bf16 planes in MFMA-fragment order (BK=16 tiles):
//   plane[p] layout [ktt(64)][nsg(16)][lane(64)][8]
//   element (n,k): ktt=k>>4, kh=(k>>3)&1, l=(n&31)|(kh<<5), j=k&7, nsg=n>>5
// ---------------------------------------------------------------------------
__global__ __launch_bounds__(256) void wsplit_kernel(
    const float* __restrict__ W, ushort* __restrict__ wsp)
{
    const int t = blockIdx.x * 256 + threadIdx.x;   // 65536 threads
    const int n = t >> 7, kq = t & 127, k0 = kq * 8;
    const float* wp = W + (size_t)n * I_SZ + k0;

    uint q1[4], q2[4], q3[4];
#pragma unroll
    for (int jj = 0; jj < 4; ++jj) {
        ushort s1[2], s2[2], s3[2];
#pragma unroll
        for (int e = 0; e < 2; ++e) {
            float w0 = wp[jj * 2 + e];
            ushort a1 = f2bf_rne(w0);
            float  f1 = __uint_as_float((uint)a1 << 16);
            float  r1 = w0 - f1;
            ushort a2 = f2bf_rne(r1);
            float  f2 = __uint_as_float((uint)a2 << 16);
            float  r2 = r1 - f2;
            ushort a3 = f2bf_rne(r2);
            s1[e] = a1; s2[e] = a2; s3[e] = a3;
        }
        q1[jj] = (uint)s1[0] | ((uint)s1[1] << 16);
        q2[jj] = (uint)s2[0] | ((uint)s2[1] << 16);
        q3[jj] = (uint)s3[0] | ((uint)s3[1] << 16);
    }
    const int kh = (k0 >> 3) & 1;
    const int l = (n & 31) | (kh << 5), nsg = n >> 5;
    const size_t off = (((size_t)(k0 >> 4) * 16 + nsg) * 64 + l) * 8;
    *(uint4*)(wsp + off)             = make_uint4(q1[0], q1[1], q1[2], q1[3]);
    *(uint4*)(wsp + PLANE + off)     = make_uint4(q2[0], q2[1], q2[2], q2[3]);
    *(uint4*)(wsp + 2 * PLANE + off) = make_uint4(q3[0], q3[1], q3[2], q3[3]);
}

// ---------------------------------------------------------------------------
// MFMA GEMM: S[M][O] = X[M][K](binary) @ (W1+W2+W3)^T + bias
//   256x256 tile, 8 waves (4m x 2n), per-wave 64x128, BK=16, 64 K-tiles,
//   QUAD-buffered LDS (4 distinct __shared__ arrays -> static NoAlias),
//   prefetch distance 3, raw s_barrier + counted vmcnt (never 0 in loop).
// ---------------------------------------------------------------------------
__global__ __launch_bounds__(512, 2) void gemm_mfma3(
    const float* __restrict__ X, const ushort* __restrict__ wsp,
    const float* __restrict__ bias, float* __restrict__ S)
{
    // 4 buffers x 32KB: A tile (2048 uints = 8KB) | B tile (6144 uints = 24KB)
    __shared__ uint buf0[8192];
    __shared__ uint buf1[8192];
    __shared__ uint buf2[8192];
    __shared__ uint buf3[8192];

    const int tid  = threadIdx.x;
    const int lane = tid & 63;
    const int w    = tid >> 6;          // 0..7
    const int wm   = w >> 1, wn = w & 1;

    // bijective XCD swizzle: 256 wgs = 8 XCDs x 32
    const int bid     = blockIdx.x;
    const int logical = (bid & 7) * 32 + (bid >> 3);
    const int mb = logical >> 1, nb = logical & 1;
    const int row0 = mb * 256;

    // A staging: thread owns row arow, k-span aks..aks+8 of each 256x16 tile
    const int arow = (tid >> 6) * 32 + (tid & 31);
    const int aks  = ((tid >> 5) & 1) * 8;
    const float* pa = X + (size_t)(row0 + arow) * I_SZ + aks;
    const int adst = tid * 4;           // uint offset in A region

    // B staging: 24 x 1KB chunks per tile; wave w issues chunks 3w..3w+2
    uint bsrc[3];
    const int c0 = w * 3;
#pragma unroll
    for (int i = 0; i < 3; ++i) {
        const int c = c0 + i, p = c >> 3, r = c & 7;
        bsrc[i] = (uint)p * PLANE + (uint)((nb * 8 + r) * 512) + lane * 8;
    }

    f32x16 acc[2][4];
#pragma unroll
    for (int i = 0; i < 2; ++i)
#pragma unroll
        for (int j = 0; j < 4; ++j)
#pragma unroll
            for (int r = 0; r < 16; ++r) acc[i][j][r] = 0.f;

#define STAGE_B(KTT, BBASE) do {                                              \
    _Pragma("unroll")                                                         \
    for (int i_ = 0; i_ < 3; ++i_)                                            \
        gload_lds16(wsp + bsrc[i_] + (uint)(KTT) * 8192,                      \
                    (BBASE) + 2048 + (c0 + i_) * 256);                        \
} while (0)

#define LOAD_A(KTT, R0, R1) do {                                              \
    const float* p_ = pa + (KTT) * 16;                                        \
    R0 = *(const float4*)p_;                                                  \
    R1 = *(const float4*)(p_ + 4);                                            \
} while (0)

#define WRITE_A(BBASE, R0, R1) do {                                           \
    uint* ad_ = (BBASE) + adst;                                               \
    *(uint4*)ad_ = make_uint4(pk2(R0.x, R0.y), pk2(R0.z, R0.w),               \
                              pk2(R1.x, R1.y), pk2(R1.z, R1.w));              \
} while (0)

#define COMPUTE(CBASE) do {                                                   \
    const uint* Au_ = (CBASE);                                                \
    const uint* Bu_ = (CBASE) + 2048;                                         \
    bf16x8 af0_ = *(const bf16x8*)(Au_ + (wm * 2 + 0) * 256 + lane * 4);      \
    bf16x8 af1_ = *(const bf16x8*)(Au_ + (wm * 2 + 1) * 256 + lane * 4);      \
    __builtin_amdgcn_s_setprio(1);                                            \
    _Pragma("unroll")                                                         \
    for (int p_ = 0; p_ < 3; ++p_) {                                          \
        _Pragma("unroll")                                                     \
        for (int sn_ = 0; sn_ < 4; ++sn_) {                                   \
            bf16x8 bf_ = *(const bf16x8*)(Bu_ + (p_ * 8 + wn * 4 + sn_) * 256 \
                                          + lane * 4);                        \
            acc[0][sn_] = __builtin_amdgcn_mfma_f32_32x32x16_bf16(            \
                af0_, bf_, acc[0][sn_], 0, 0, 0);                             \
            acc[1][sn_] = __builtin_amdgcn_mfma_f32_32x32x16_bf16(            \
                af1_, bf_, acc[1][sn_], 0, 0, 0);                             \
        }                                                                     \
    }                                                                         \
    __builtin_amdgcn_s_setprio(0);                                            \
} while (0)

// Per iteration: issue 3 B-gloads(kt+3) + 2 A-loads(kt+4) = exactly 5 vm ops.
// vmcnt(5) == "all prior iterations' vm ops drained": guarantees B(kt+1)
// staged before the barrier AND A(kt+3) regs ready for the late ds_write.
#define STEP(KT, CBASE, SBASE, W0, W1, L0, L1) do {                           \
    const int kt_ = (KT);                                                     \
    if (kt_ <= 60) STAGE_B(kt_ + 3, SBASE);                                   \
    if (kt_ <= 59) LOAD_A(kt_ + 4, L0, L1);                                   \
    COMPUTE(CBASE);                                                           \
    if (kt_ <= 59)      asm volatile("s_waitcnt vmcnt(5)" ::: "memory");      \
    else if (kt_ == 60) asm volatile("s_waitcnt vmcnt(3)" ::: "memory");      \
    else if (kt_ == 61) asm volatile("s_waitcnt vmcnt(0)" ::: "memory");      \
    if (kt_ <= 60) WRITE_A(SBASE, W0, W1);                                    \
    if (kt_ < 63) {                                                           \
        asm volatile("s_waitcnt lgkmcnt(0)" ::: "memory");                    \
        __builtin_amdgcn_s_barrier();                                         \
        __builtin_amdgcn_sched_barrier(0);                                    \
    }                                                                         \
} while (0)

    float4 awa = {0,0,0,0}, awb = {0,0,0,0}, axa = {0,0,0,0}, axb = {0,0,0,0};

    // ---- prologue: stage tiles 0,1,2; preload A(3) regs
    {
        float4 t0a, t0b, t1a, t1b, t2a, t2b;
        STAGE_B(0, buf0); STAGE_B(1, buf1); STAGE_B(2, buf2);
        LOAD_A(0, t0a, t0b); LOAD_A(1, t1a, t1b); LOAD_A(2, t2a, t2b);
        asm volatile("s_waitcnt vmcnt(0)" ::: "memory");
        WRITE_A(buf0, t0a, t0b);
        WRITE_A(buf1, t1a, t1b);
        WRITE_A(buf2, t2a, t2b);
        LOAD_A(3, awa, awb);
        asm volatile("s_waitcnt lgkmcnt(0)" ::: "memory");
        __builtin_amdgcn_s_barrier();
        __builtin_amdgcn_sched_barrier(0);
    }

    for (int kt = 0; kt < 64; kt += 4) {
        STEP(kt + 0, buf0, buf3, awa, awb, axa, axb);
        STEP(kt + 1, buf1, buf0, axa, axb, awa, awb);
        STEP(kt + 2, buf2, buf1, awa, awb, axa, axb);
        STEP(kt + 3, buf3, buf2, axa, axb, awa, awb);
    }

    // epilogue: D row=(reg&3)+8*(reg>>2)+4*(lane>>5), col=lane&31 (B operand)
    const int colb = nb * 256 + wn * 128 + (lane & 31);
    const int rowb = row0 + wm * 64 + 4 * (lane >> 5);
    float bv[4];
#pragma unroll
    for (int sn = 0; sn < 4; ++sn) bv[sn] = bias[colb + sn * 32];
#pragma unroll
    for (int sm = 0; sm < 2; ++sm)
#pragma unroll
        for (int sn = 0; sn < 4; ++sn)
#pragma unroll
            for (int r = 0; r < 16; ++r) {
                const int rr = rowb + sm * 32 + (r & 3) + 8 * (r >> 2);
                S[(size_t)rr * O_SZ + colb + sn * 32] = acc[sm][sn][r] + bv[sn];
            }
#undef STAGE_B
#undef LOAD_A
#undef WRITE_A
#undef COMPUTE
#undef STEP
}

// ---------------------------------------------------------------------------
// Fallback fp32 GEMM if ws too small for split planes.
// ---------------------------------------------------------------------------
#define BM 128
#define BN 128
#define BKF 32
#define LDT 132

__global__ __launch_bounds__(256, 2) void gemm_fp32(
    const float* __restrict__ X, const float* __restrict__ W,
    const float* __restrict__ bias, float* __restrict__ S)
{
    __shared__ float As[BKF][LDT];
    __shared__ float Ws[BKF][LDT];
    const int tid = threadIdx.x;
    const int nb = blockIdx.x & 3;
    const int mb = blockIdx.x >> 2;
    const int tx = (tid & 7) | ((tid & 128) >> 4);
    const int ty = (tid >> 3) & 15;
    const float* Ablk = X + (size_t)mb * BM * I_SZ;
    const float* Wblk = W + (size_t)nb * BN * I_SZ;
    const int skq = tid & 7;
    const int srow = tid >> 3;
    float acc[8][8];
#pragma unroll
    for (int i = 0; i < 8; ++i)
#pragma unroll
        for (int j = 0; j < 8; ++j) acc[i][j] = 0.f;
    for (int kt = 0; kt < I_SZ; kt += BKF) {
#pragma unroll
        for (int it = 0; it < 4; ++it) {
            const int row = srow + it * 32;
            float4 a = *(const float4*)(Ablk + (size_t)row * I_SZ + kt + skq * 4);
            As[skq * 4 + 0][row] = a.x; As[skq * 4 + 1][row] = a.y;
            As[skq * 4 + 2][row] = a.z; As[skq * 4 + 3][row] = a.w;
            float4 wv = *(const float4*)(Wblk + (size_t)row * I_SZ + kt + skq * 4);
            Ws[skq * 4 + 0][row] = wv.x; Ws[skq * 4 + 1][row] = wv.y;
            Ws[skq * 4 + 2][row] = wv.z; Ws[skq * 4 + 3][row] = wv.w;
        }
        __syncthreads();
#pragma unroll
        for (int kk = 0; kk < BKF; ++kk) {
            float4 a0 = *(const float4*)&As[kk][ty * 8];
            float4 a1 = *(const float4*)&As[kk][ty * 8 + 4];
            float4 w0 = *(const float4*)&Ws[kk][tx * 8];
            float4 w1 = *(const float4*)&Ws[kk][tx * 8 + 4];
            float av[8] = {a0.x, a0.y, a0.z, a0.w, a1.x, a1.y, a1.z, a1.w};
            float wv[8] = {w0.x, w0.y, w0.z, w0.w, w1.x, w1.y, w1.z, w1.w};
#pragma unroll
            for (int i = 0; i < 8; ++i)
#pragma unroll
                for (int j = 0; j < 8; ++j) acc[i][j] += av[i] * wv[j];
        }
        __syncthreads();
    }
    const int row0 = mb * BM + ty * 8;
    const int col0 = nb * BN + tx * 8;
    float bv[8];
#pragma unroll
    for (int j = 0; j < 8; ++j) bv[j] = bias[col0 + j];
#pragma unroll
    for (int i = 0; i < 8; ++i) {
        float4 o0 = {acc[i][0] + bv[0], acc[i][1] + bv[1], acc[i][2] + bv[2], acc[i][3] + bv[3]};
        float4 o1 = {acc[i][4] + bv[4], acc[i][5] + bv[5], acc[i][6] + bv[6], acc[i][7] + bv[7]};
        *(float4*)(S + (size_t)(row0 + i) * O_SZ + col0)     = o0;
        *(float4*)(S + (size_t)(row0 + i) * O_SZ + col0 + 4) = o1;
    }
}

// ---------------------------------------------------------------------------
// Fused scan + tpre. Blocks 0..255: per-(b,o) temporal scan (burst prefetch:
// load next 8 t-values BEFORE the serial compute block). Blocks 256..767:
// times_pre backward search. Co-residency: tpre waves hide scan load latency.
// ---------------------------------------------------------------------------
__global__ __launch_bounds__(256) void scan_tpre_kernel(
    float* __restrict__ out, const float* __restrict__ wl_arr,
    const float* __restrict__ x)
{
    const int bid = blockIdx.x;
    if (bid < 256) {
#pragma clang fp contract(off)
        const int gid = bid * 256 + threadIdx.x;   // b*O + o
        const float wl = wl_arr[gid & (O_SZ - 1)];
        const float decay_s = 0.8f;
        const float decay_m = 0.9f;

        float cur[8], nxt[8];
#pragma unroll
        for (int i = 0; i < 8; ++i) cur[i] = out[(size_t)i * (B_SZ * O_SZ) + gid];

        float ep = 0.f, u = 0.f, osp = 0.f, vref = 0.f, tpost = -1.f;
        for (int tb = 0; tb < T_STEPS; tb += 8) {
            if (tb < T_STEPS - 8) {
#pragma unroll
                for (int i = 0; i < 8; ++i)
                    nxt[i] = out[(size_t)(tb + 8 + i) * (B_SZ * O_SZ) + gid];
            }
#pragma unroll
            for (int i = 0; i < 8; ++i) {
                const int t = tb + i;
                const size_t idx = (size_t)t * (B_SZ * O_SZ) + gid;
                float iresp = cur[i] + osp * wl;
                ep = ep * decay_s + iresp;
                u  = u * decay_m + ep / 5.0f;
                if (vref > 0.f) u = 0.f;
                osp = (u > 1.0f) ? 1.f : 0.f;
                float v = 2.0f * osp + (vref - 1.0f);
                vref = v < 0.f ? 0.f : (v > 2.f ? 2.f : v);
                float cand = osp * ((float)t + 1.0f) - 1.0f;
                tpost = cand > tpost ? cand : tpost;
                out[idx] = osp;
            }
#pragma unroll
            for (int i = 0; i < 8; ++i) cur[i] = nxt[i];
        }
        out[(size_t)T_STEPS * B_SZ * O_SZ + (size_t)B_SZ * I_SZ + gid] = tpost;
    } else {
        const int gid = (bid - 256) * 256 + threadIdx.x;   // b*I + i
        float tp = -1.f;
        for (int t = T_STEPS - 1; t >= 0; --t) {
            if (x[(size_t)t * (B_SZ * I_SZ) + gid] > 0.5f) { tp = (float)t; break; }
        }
        out[(size_t)T_STEPS * B_SZ * O_SZ + gid] = tp;
    }
}

// ---------------------------------------------------------------------------
extern "C" void kernel_launch(void* const* d_in, const int* in_sizes, int n_in,
                              void* d_out, int out_size, void* d_ws, size_t ws_size,
                              hipStream_t stream) {
    const float* x    = (const float*)d_in[0];
    const float* w    = (const float*)d_in[1];
    const float* bias = (const float*)d_in[2];
    const float* wl   = (const float*)d_in[3];
    float* out = (float*)d_out;

    if (ws_size >= WS_NEEDED) {
        ushort* wsp = (ushort*)d_ws;
        wsplit_kernel<<<dim3(256), dim3(256), 0, stream>>>(w, wsp);
        gemm_mfma3<<<dim3(256), dim3(512), 0, stream>>>(x, wsp, bias, out);
    } else {
        gemm_fp32<<<dim3(1024), dim3(256), 0, stream>>>(x, w, bias, out);
    }
    scan_tpre_kernel<<<dim3(768), dim3(256), 0, stream>>>(out, wl, x);
}

// Round 5
// 139.378 us; speedup vs baseline: 1.5266x; 1.0537x over previous
//
#include <hip/hip_runtime.h>

#define T_STEPS 256
#define B_SZ 128
#define I_SZ 1024
#define O_SZ 512

typedef short bf16x8 __attribute__((ext_vector_type(8)));
typedef float f32x16 __attribute__((ext_vector_type(16)));

#define PLANE (O_SZ * I_SZ)                 // ushorts per split plane
#define WS_NEEDED ((size_t)3 * PLANE * 2)   // 3 MB

// ---------------------------------------------------------------------------
// helpers
// ---------------------------------------------------------------------------
__device__ __forceinline__ ushort f2bf_rne(float f) {
    uint u = __float_as_uint(f);
    u += ((u >> 16) & 1u) + 0x7fffu;        // round-to-nearest-even
    return (ushort)(u >> 16);
}
__device__ __forceinline__ uint pk2(float lo, float hi) {
    // exact for x in {0,1}: truncation == RNE
    return (__float_as_uint(lo) >> 16) | (__float_as_uint(hi) & 0xffff0000u);
}
__device__ __forceinline__ void gload_lds16(const void* g, void* l) {
    typedef const void __attribute__((address_space(1))) gvt;
    typedef void __attribute__((address_space(3))) svt;
    __builtin_amdgcn_global_load_lds((gvt*)g, (svt*)l, 16, 0, 0);
}

// ---------------------------------------------------------------------------
// W split: W[n][k] fp32 -> 3 bf16 planes in MFMA-fragment order (BK=32 tiles):
//   plane[p] layout [kt(32)][nsg(16)][k16(2)][lane(64)][8]
//   element (n,k): kt=k>>5, k16=(k>>4)&1, kh=(k>>3)&1, l=(n&31)|(kh<<5),
//   j=k&7, nsg=n>>5
// ---------------------------------------------------------------------------
__global__ __launch_bounds__(256) void wsplit_kernel(
    const float* __restrict__ W, ushort* __restrict__ wsp)
{
    const int t = blockIdx.x * 256 + threadIdx.x;   // 65536 threads
    const int n = t >> 7, kq = t & 127, k0 = kq * 8;
    const float* wp = W + (size_t)n * I_SZ + k0;

    uint q1[4], q2[4], q3[4];
#pragma unroll
    for (int jj = 0; jj < 4; ++jj) {
        ushort s1[2], s2[2], s3[2];
#pragma unroll
        for (int e = 0; e < 2; ++e) {
            float w0 = wp[jj * 2 + e];
            ushort a1 = f2bf_rne(w0);
            float  f1 = __uint_as_float((uint)a1 << 16);
            float  r1 = w0 - f1;
            ushort a2 = f2bf_rne(r1);
            float  f2 = __uint_as_float((uint)a2 << 16);
            float  r2 = r1 - f2;
            ushort a3 = f2bf_rne(r2);
            s1[e] = a1; s2[e] = a2; s3[e] = a3;
        }
        q1[jj] = (uint)s1[0] | ((uint)s1[1] << 16);
        q2[jj] = (uint)s2[0] | ((uint)s2[1] << 16);
        q3[jj] = (uint)s3[0] | ((uint)s3[1] << 16);
    }
    const int kt = k0 >> 5, k16 = (k0 >> 4) & 1, kh = (k0 >> 3) & 1;
    const int l = (n & 31) | (kh << 5), nsg = n >> 5;
    const size_t off = ((((size_t)kt * 16 + nsg) * 2 + k16) * 64 + l) * 8;
    *(uint4*)(wsp + off)             = make_uint4(q1[0], q1[1], q1[2], q1[3]);
    *(uint4*)(wsp + PLANE + off)     = make_uint4(q2[0], q2[1], q2[2], q2[3]);
    *(uint4*)(wsp + 2 * PLANE + off) = make_uint4(q3[0], q3[1], q3[2], q3[3]);
}

// ---------------------------------------------------------------------------
// MFMA GEMM: S[M][O] = X[M][K](binary) @ (W1+W2+W3)^T + bias
//   256x256 tile, 8 waves as 2m x 4n, per-wave 128x64 (M_rep=4, N_rep=2),
//   BK=32, double-buffered LDS (A 2x16KB + B 2x48KB = 128KB), dist-1 prefetch.
//   A-frags register-cached across the 3 planes; B-frags register-prefetched
//   plane-ahead so ds_reads interleave with the 16-MFMA clusters.
// ---------------------------------------------------------------------------
__global__ __launch_bounds__(512, 2) void gemm_mfma4(
    const float* __restrict__ X, const ushort* __restrict__ wsp,
    const float* __restrict__ bias, float* __restrict__ S)
{
    __shared__ uint ldsA[8192];    // 2 x 4096 uints (16 KB each)
    __shared__ uint ldsB[24576];   // 2 x 12288 uints (48 KB each)

    const int tid  = threadIdx.x;
    const int lane = tid & 63;
    const int w    = tid >> 6;          // 0..7
    const int wm   = w >> 2, wn = w & 3;

    // bijective XCD swizzle: 256 wgs = 8 XCDs x 32; nb-pairs of same mb adjacent
    const int bid     = blockIdx.x;
    const int logical = (bid & 7) * 32 + (bid >> 3);
    const int mb = logical >> 1, nb = logical & 1;
    const int row0 = mb * 256;

    // ---- A staging (coalesced): instr i: row = w*32 + i*8 + (lane>>3),
    //      k-quad kq = lane&7 -> float4 covers k = kq*4..kq*4+3 of that row.
    const int arow = w * 32 + (lane >> 3);
    const int akq  = lane & 7;
    const float* pa = X + (size_t)(row0 + arow) * I_SZ + akq * 4;
    // fragment dest (uint offset + half-slot selector) for (row, kq):
    //   msub=row>>5, s=kq>>2, lane'=(row&31)|(((kq>>1)&1)<<5), j0=(kq&1)*4
    uint adst[4];
#pragma unroll
    for (int i = 0; i < 4; ++i) {
        const int row = arow + i * 8;
        adst[i] = (((row >> 5) * 2 + (akq >> 2)) * 64 +
                   ((row & 31) | (((akq >> 1) & 1) << 5))) * 4 + (akq & 1) * 2;
    }

    // ---- B staging: 48 x 1KB chunks per K-step; wave w issues chunks 6w..6w+5
    //      chunk c = p*16 + r*2 + k16  (r = local nsg 0..7)
    uint bsrc[6];
    const int c0 = w * 6;
#pragma unroll
    for (int i = 0; i < 6; ++i) {
        const int c = c0 + i, p = c >> 4, rr = (c >> 1) & 7, k16 = c & 1;
        bsrc[i] = (uint)p * PLANE + (uint)(((nb * 8 + rr) * 2 + k16) * 512) + lane * 8;
    }

    f32x16 acc[4][2];
#pragma unroll
    for (int i = 0; i < 4; ++i)
#pragma unroll
        for (int j = 0; j < 2; ++j)
#pragma unroll
            for (int r = 0; r < 16; ++r) acc[i][j][r] = 0.f;

#define BFRAG(BASE, P, SN, SS) \
    (*(const bf16x8*)((BASE) + (((P) * 8 + wn * 2 + (SN)) * 2 + (SS)) * 256 + lane * 4))

#define CLUSTER(B00, B01, B10, B11) do {                                      \
    __builtin_amdgcn_s_setprio(1);                                            \
    _Pragma("unroll")                                                         \
    for (int m_ = 0; m_ < 4; ++m_) {                                          \
        acc[m_][0] = __builtin_amdgcn_mfma_f32_32x32x16_bf16(af[m_][0], B00, acc[m_][0], 0, 0, 0); \
        acc[m_][0] = __builtin_amdgcn_mfma_f32_32x32x16_bf16(af[m_][1], B01, acc[m_][0], 0, 0, 0); \
        acc[m_][1] = __builtin_amdgcn_mfma_f32_32x32x16_bf16(af[m_][0], B10, acc[m_][1], 0, 0, 0); \
        acc[m_][1] = __builtin_amdgcn_mfma_f32_32x32x16_bf16(af[m_][1], B11, acc[m_][1], 0, 0, 0); \
    }                                                                         \
    __builtin_amdgcn_s_setprio(0);                                            \
} while (0)

    // ---- prologue: stage kt=0 into buffer 0
    {
#pragma unroll
        for (int i = 0; i < 6; ++i)
            gload_lds16(wsp + bsrc[i], ldsB + (c0 + i) * 256);
        float4 a0 = *(const float4*)(pa);
        float4 a1 = *(const float4*)(pa + 8 * I_SZ);
        float4 a2 = *(const float4*)(pa + 16 * I_SZ);
        float4 a3 = *(const float4*)(pa + 24 * I_SZ);
        *(uint2*)(ldsA + adst[0]) = make_uint2(pk2(a0.x, a0.y), pk2(a0.z, a0.w));
        *(uint2*)(ldsA + adst[1]) = make_uint2(pk2(a1.x, a1.y), pk2(a1.z, a1.w));
        *(uint2*)(ldsA + adst[2]) = make_uint2(pk2(a2.x, a2.y), pk2(a2.z, a2.w));
        *(uint2*)(ldsA + adst[3]) = make_uint2(pk2(a3.x, a3.y), pk2(a3.z, a3.w));
        __syncthreads();
    }

    for (int kt = 0; kt < 32; ++kt) {
        const int cur = kt & 1;
        const uint* Ac = ldsA + cur * 4096;
        const uint* Bc = ldsB + cur * 12288;
        uint* An = ldsA + (cur ^ 1) * 4096;
        uint* Bn = ldsB + (cur ^ 1) * 12288;
        const bool pref = (kt < 31);

        // dist-1 prefetch: issue next tile's loads first (drained by step end)
        float4 a0, a1, a2, a3;
        if (pref) {
            const uint kadd = (uint)(kt + 1) * 16384;
#pragma unroll
            for (int i = 0; i < 6; ++i)
                gload_lds16(wsp + bsrc[i] + kadd, Bn + (c0 + i) * 256);
            const float* p_ = pa + (kt + 1) * 32;
            a0 = *(const float4*)(p_);
            a1 = *(const float4*)(p_ + 8 * I_SZ);
            a2 = *(const float4*)(p_ + 16 * I_SZ);
            a3 = *(const float4*)(p_ + 24 * I_SZ);
        }

        // A fragments for this step: register-cached across all 3 planes
        bf16x8 af[4][2];
#pragma unroll
        for (int m = 0; m < 4; ++m)
#pragma unroll
            for (int s = 0; s < 2; ++s)
                af[m][s] = *(const bf16x8*)(Ac + (((wm * 4 + m) * 2 + s) * 64 + lane) * 4);

        // plane 0 frags + plane 1 prefetch, then clusters with read-ahead
        bf16x8 c00 = BFRAG(Bc, 0, 0, 0), c01 = BFRAG(Bc, 0, 0, 1);
        bf16x8 c10 = BFRAG(Bc, 0, 1, 0), c11 = BFRAG(Bc, 0, 1, 1);
        bf16x8 n00 = BFRAG(Bc, 1, 0, 0), n01 = BFRAG(Bc, 1, 0, 1);
        bf16x8 n10 = BFRAG(Bc, 1, 1, 0), n11 = BFRAG(Bc, 1, 1, 1);
        CLUSTER(c00, c01, c10, c11);                       // plane 0
        c00 = BFRAG(Bc, 2, 0, 0); c01 = BFRAG(Bc, 2, 0, 1);
        c10 = BFRAG(Bc, 2, 1, 0); c11 = BFRAG(Bc, 2, 1, 1);
        CLUSTER(n00, n01, n10, n11);                       // plane 1
        CLUSTER(c00, c01, c10, c11);                       // plane 2

        // late A write into next buffer (global loads drained under MFMAs)
        if (pref) {
            *(uint2*)(An + adst[0]) = make_uint2(pk2(a0.x, a0.y), pk2(a0.z, a0.w));
            *(uint2*)(An + adst[1]) = make_uint2(pk2(a1.x, a1.y), pk2(a1.z, a1.w));
            *(uint2*)(An + adst[2]) = make_uint2(pk2(a2.x, a2.y), pk2(a2.z, a2.w));
            *(uint2*)(An + adst[3]) = make_uint2(pk2(a3.x, a3.y), pk2(a3.z, a3.w));
        }
        __syncthreads();
    }

    // epilogue: D row=(reg&3)+8*(reg>>2)+4*(lane>>5), col=lane&31 (B operand)
    const int colb = nb * 256 + wn * 64 + (lane & 31);
    const int rowbase = row0 + wm * 128 + 4 * (lane >> 5);
    float bv[2];
#pragma unroll
    for (int sn = 0; sn < 2; ++sn) bv[sn] = bias[colb + sn * 32];
#pragma unroll
    for (int m = 0; m < 4; ++m)
#pragma unroll
        for (int sn = 0; sn < 2; ++sn)
#pragma unroll
            for (int r = 0; r < 16; ++r) {
                const int rr = rowbase + m * 32 + (r & 3) + 8 * (r >> 2);
                S[(size_t)rr * O_SZ + colb + sn * 32] = acc[m][sn][r] + bv[sn];
            }
#undef BFRAG
#undef CLUSTER
}

// ---------------------------------------------------------------------------
// Fallback fp32 GEMM if ws too small for split planes.
// ---------------------------------------------------------------------------
#define BM 128
#define BN 128
#define BKF 32
#define LDT 132

__global__ __launch_bounds__(256, 2) void gemm_fp32(
    const float* __restrict__ X, const float* __restrict__ W,
    const float* __restrict__ bias, float* __restrict__ S)
{
    __shared__ float As[BKF][LDT];
    __shared__ float Ws[BKF][LDT];
    const int tid = threadIdx.x;
    const int nb = blockIdx.x & 3;
    const int mb = blockIdx.x >> 2;
    const int tx = (tid & 7) | ((tid & 128) >> 4);
    const int ty = (tid >> 3) & 15;
    const float* Ablk = X + (size_t)mb * BM * I_SZ;
    const float* Wblk = W + (size_t)nb * BN * I_SZ;
    const int skq = tid & 7;
    const int srow = tid >> 3;
    float acc[8][8];
#pragma unroll
    for (int i = 0; i < 8; ++i)
#pragma unroll
        for (int j = 0; j < 8; ++j) acc[i][j] = 0.f;
    for (int kt = 0; kt < I_SZ; kt += BKF) {
#pragma unroll
        for (int it = 0; it < 4; ++it) {
            const int row = srow + it * 32;
            float4 a = *(const float4*)(Ablk + (size_t)row * I_SZ + kt + skq * 4);
            As[skq * 4 + 0][row] = a.x; As[skq * 4 + 1][row] = a.y;
            As[skq * 4 + 2][row] = a.z; As[skq * 4 + 3][row] = a.w;
            float4 wv = *(const float4*)(Wblk + (size_t)row * I_SZ + kt + skq * 4);
            Ws[skq * 4 + 0][row] = wv.x; Ws[skq * 4 + 1][row] = wv.y;
            Ws[skq * 4 + 2][row] = wv.z; Ws[skq * 4 + 3][row] = wv.w;
        }
        __syncthreads();
#pragma unroll
        for (int kk = 0; kk < BKF; ++kk) {
            float4 a0 = *(const float4*)&As[kk][ty * 8];
            float4 a1 = *(const float4*)&As[kk][ty * 8 + 4];
            float4 w0 = *(const float4*)&Ws[kk][tx * 8];
            float4 w1 = *(const float4*)&Ws[kk][tx * 8 + 4];
            float av[8] = {a0.x, a0.y, a0.z, a0.w, a1.x, a1.y, a1.z, a1.w};
            float wv[8] = {w0.x, w0.y, w0.z, w0.w, w1.x, w1.y, w1.z, w1.w};
#pragma unroll
            for (int i = 0; i < 8; ++i)
#pragma unroll
                for (int j = 0; j < 8; ++j) acc[i][j] += av[i] * wv[j];
        }
        __syncthreads();
    }
    const int row0 = mb * BM + ty * 8;
    const int col0 = nb * BN + tx * 8;
    float bv[8];
#pragma unroll
    for (int j = 0; j < 8; ++j) bv[j] = bias[col0 + j];
#pragma unroll
    for (int i = 0; i < 8; ++i) {
        float4 o0 = {acc[i][0] + bv[0], acc[i][1] + bv[1], acc[i][2] + bv[2], acc[i][3] + bv[3]};
        float4 o1 = {acc[i][4] + bv[4], acc[i][5] + bv[5], acc[i][6] + bv[6], acc[i][7] + bv[7]};
        *(float4*)(S + (size_t)(row0 + i) * O_SZ + col0)     = o0;
        *(float4*)(S + (size_t)(row0 + i) * O_SZ + col0 + 4) = o1;
    }
}

// ---------------------------------------------------------------------------
// Fused scan + tpre. Blocks 0..255: per-(b,o) temporal scan (burst prefetch).
// Blocks 256..767: times_pre backward search. Co-resident for latency hiding.
// ---------------------------------------------------------------------------
__global__ __launch_bounds__(256) void scan_tpre_kernel(
    float* __restrict__ out, const float* __restrict__ wl_arr,
    const float* __restrict__ x)
{
    const int bid = blockIdx.x;
    if (bid < 256) {
#pragma clang fp contract(off)
        const int gid = bid * 256 + threadIdx.x;   // b*O + o
        const float wl = wl_arr[gid & (O_SZ - 1)];
        const float decay_s = 0.8f;
        const float decay_m = 0.9f;

        float cur[8], nxt[8];
#pragma unroll
        for (int i = 0; i < 8; ++i) cur[i] = out[(size_t)i * (B_SZ * O_SZ) + gid];

        float ep = 0.f, u = 0.f, osp = 0.f, vref = 0.f, tpost = -1.f;
        for (int tb = 0; tb < T_STEPS; tb += 8) {
            if (tb < T_STEPS - 8) {
#pragma unroll
                for (int i = 0; i < 8; ++i)
                    nxt[i] = out[(size_t)(tb + 8 + i) * (B_SZ * O_SZ) + gid];
            }
#pragma unroll
            for (int i = 0; i < 8; ++i) {
                const int t = tb + i;
                const size_t idx = (size_t)t * (B_SZ * O_SZ) + gid;
                float iresp = cur[i] + osp * wl;
                ep = ep * decay_s + iresp;
                u  = u * decay_m + ep / 5.0f;
                if (vref > 0.f) u = 0.f;
                osp = (u > 1.0f) ? 1.f : 0.f;
                float v = 2.0f * osp + (vref - 1.0f);
                vref = v < 0.f ? 0.f : (v > 2.f ? 2.f : v);
                float cand = osp * ((float)t + 1.0f) - 1.0f;
                tpost = cand > tpost ? cand : tpost;
                out[idx] = osp;
            }
#pragma unroll
            for (int i = 0; i < 8; ++i) cur[i] = nxt[i];
        }
        out[(size_t)T_STEPS * B_SZ * O_SZ + (size_t)B_SZ * I_SZ + gid] = tpost;
    } else {
        const int gid = (bid - 256) * 256 + threadIdx.x;   // b*I + i
        float tp = -1.f;
        for (int t = T_STEPS - 1; t >= 0; --t) {
            if (x[(size_t)t * (B_SZ * I_SZ) + gid] > 0.5f) { tp = (float)t; break; }
        }
        out[(size_t)T_STEPS * B_SZ * O_SZ + gid] = tp;
    }
}

// ---------------------------------------------------------------------------
extern "C" void kernel_launch(void* const* d_in, const int* in_sizes, int n_in,
                              void* d_out, int out_size, void* d_ws, size_t ws_size,
                              hipStream_t stream) {
    const float* x    = (const float*)d_in[0];
    const float* w    = (const float*)d_in[1];
    const float* bias = (const float*)d_in[2];
    const float* wl   = (const float*)d_in[3];
    float* out = (float*)d_out;

    if (ws_size >= WS_NEEDED) {
        ushort* wsp = (ushort*)d_ws;
        wsplit_kernel<<<dim3(256), dim3(256), 0, stream>>>(w, wsp);
        gemm_mfma4<<<dim3(256), dim3(512), 0, stream>>>(x, wsp, bias, out);
    } else {
        gemm_fp32<<<dim3(1024), dim3(256), 0, stream>>>(x, w, bias, out);
    }
    scan_tpre_kernel<<<dim3(768), dim3(256), 0, stream>>>(out, wl, x);
}